// Round 9
// baseline (262.476 us; speedup 1.0000x reference)
//
#include <hip/hip_runtime.h>
#include <hip/hip_bf16.h>
#include <math.h>

typedef __hip_bfloat16 bf16;
typedef __attribute__((ext_vector_type(8))) short bf16x8;
typedef __attribute__((ext_vector_type(4))) float f32x4;
typedef __attribute__((ext_vector_type(4))) unsigned int u32x4;

#define N_NODES 10000
#define N_EDGES 160000
#define IN_C    768
#define H1DIM   1024      // HEADS * HID
#define HEADS   4
#define OUT_C   256
#define NEG_SLOPE 0.2f

__device__ __forceinline__ float u2f(unsigned short u) { return __uint_as_float(((unsigned)u) << 16); }
__device__ __forceinline__ float lo2f(unsigned u) { return __uint_as_float(u << 16); }
__device__ __forceinline__ float hi2f(unsigned u) { return __uint_as_float(u & 0xFFFF0000u); }

// ---------------- fused prep: cvt x->bf16, transpose W1/W2, zero (r15 proven) -------
#define CVT_BLOCKS 7500                    // 10000*768/4 / 256  (exact)
#define T1_BLOCKS  768                     // (1024/32) x (768/32)
#define T2_BLOCKS  256                     // (256/32) x (1024/32)
#define Z_WORDS    140096                  // as1+ad1+as2+ad2+degs span (with carve pads)/4
#define Z_BLOCKS   548                     // ceil(Z_WORDS/256)

__global__ __launch_bounds__(256) void prep_kernel(
    const float* __restrict__ x, bf16* __restrict__ xb,
    const float* __restrict__ W1, bf16* __restrict__ W1t,
    const float* __restrict__ W2, bf16* __restrict__ W2t,
    int* __restrict__ zbase)
{
    __shared__ float tile[32][33];
    const int bid = blockIdx.x;
    const int tid = threadIdx.x;
    if (bid < CVT_BLOCKS) {
        const int i = bid * 256 + tid;
        const float4 v = *((const float4*)x + i);
        bf16* d = xb + (size_t)i * 4;
        d[0] = __float2bfloat16(v.x); d[1] = __float2bfloat16(v.y);
        d[2] = __float2bfloat16(v.z); d[3] = __float2bfloat16(v.w);
        return;
    }
    if (bid < CVT_BLOCKS + T1_BLOCKS + T2_BLOCKS) {
        const bool isW1 = bid < CVT_BLOCKS + T1_BLOCKS;
        const int lb = isW1 ? (bid - CVT_BLOCKS) : (bid - CVT_BLOCKS - T1_BLOCKS);
        const int TX = isW1 ? (H1DIM / 32) : (OUT_C / 32);
        const int R  = isW1 ? IN_C : H1DIM;      // src rows
        const int C  = isW1 ? H1DIM : OUT_C;     // src cols
        const float* src = isW1 ? W1 : W2;
        bf16* dst = isW1 ? W1t : W2t;
        const int bc = (lb % TX) * 32;
        const int br = (lb / TX) * 32;
        const int tx = tid & 31, ty = tid >> 5;
        #pragma unroll
        for (int i = ty; i < 32; i += 8)
            tile[i][tx] = src[(size_t)(br + i) * C + bc + tx];
        __syncthreads();
        #pragma unroll
        for (int i = ty; i < 32; i += 8)
            dst[(size_t)(bc + i) * R + br + tx] = __float2bfloat16(tile[tx][i]);
        return;
    }
    const int i = (bid - CVT_BLOCKS - T1_BLOCKS - T2_BLOCKS) * 256 + tid;
    if (i < Z_WORDS) zbase[i] = 0;
}

// ---------------- CSR build ----------------
__global__ void count_deg(const int* __restrict__ ei, int* __restrict__ deg_d, int* __restrict__ deg_s) {
    const int e = blockIdx.x * blockDim.x + threadIdx.x;
    if (e >= N_EDGES) return;
    atomicAdd(&deg_d[ei[N_EDGES + e]], 1);
    atomicAdd(&deg_s[ei[e]], 1);
}

__global__ __launch_bounds__(1024) void scan_fast2(const int* __restrict__ deg_d, int* __restrict__ offs_d,
                                                   const int* __restrict__ deg_s, int* __restrict__ offs_s,
                                                   int n) {
    const int* deg = blockIdx.x ? deg_s : deg_d;
    int* offs      = blockIdx.x ? offs_s : offs_d;
    const int t = threadIdx.x;
    const int iter = (n + 1023) >> 10;
    const int base = t * iter;
    int ex[16];
    int sum = 0;
    for (int j = 0; j < iter; ++j) {
        const int i = base + j;
        const int v = (i < n) ? deg[i] : 0;
        ex[j] = sum;
        sum += v;
    }
    const int lane = t & 63, w = t >> 6;
    int inc = sum;
    #pragma unroll
    for (int o = 1; o < 64; o <<= 1) {
        const int x = __shfl_up(inc, o);
        if (lane >= o) inc += x;
    }
    __shared__ int wtot[16];
    if (lane == 63) wtot[w] = inc;
    __syncthreads();
    if (t == 0) {
        int c = 0;
        #pragma unroll
        for (int i = 0; i < 16; ++i) { const int x = wtot[i]; wtot[i] = c; c += x; }
    }
    __syncthreads();
    const int tbase = wtot[w] + inc - sum;
    for (int j = 0; j < iter; ++j) {
        const int i = base + j;
        if (i < n) offs[i] = tbase + ex[j];
    }
    if (t == 1023) offs[n] = tbase + sum;
}

// stores NEIGHBOR NODE id directly (r20): dst-CSR holds src node, src-CSR holds dst node
__global__ void fill_csr(const int* __restrict__ ei,
                         const int* __restrict__ offs_d, const int* __restrict__ offs_s,
                         int* __restrict__ cur_d, int* __restrict__ cur_s,
                         int* __restrict__ nbr_d, int* __restrict__ nbr_s) {
    const int e = blockIdx.x * blockDim.x + threadIdx.x;
    if (e >= N_EDGES) return;
    const int s = ei[e];
    const int d = ei[N_EDGES + e];
    const int p = atomicAdd(&cur_d[d], 1);
    nbr_d[offs_d[d] + p] = s;
    const int q = atomicAdd(&cur_s[s], 1);
    nbr_s[offs_s[s] + q] = d;
}

// ------- MFMA NT GEMM 128x64 (r15 reg-dbuf staging, proven) + fused att dots (r24) --
__global__ __launch_bounds__(256) void gemm_mfma64(const bf16* __restrict__ A,
                                                   const bf16* __restrict__ Bt,
                                                   bf16* __restrict__ C,
                                                   const float* __restrict__ ws_,
                                                   const float* __restrict__ wd_,
                                                   float* __restrict__ a_s,
                                                   float* __restrict__ a_d,
                                                   int M, int N, int K) {
    __shared__ short lds_a[128 * 5 * 8];
    __shared__ short lds_b[64 * 5 * 8];
    const int bm = blockIdx.y * 128;
    const int bn = blockIdx.x * 64;
    const int t = threadIdx.x;
    const int lane = t & 63;
    const int wv = t >> 6;
    const int fm = lane & 15;
    const int fq = lane >> 4;

    const short* ap0 = lds_a + ((wv * 32 + fm) * 5 + fq) * 8;
    const short* ap1 = ap0 + 16 * 5 * 8;
    const short* bp0 = lds_b + ((fm) * 5 + fq) * 8;
    const short* bp1 = bp0 + 16 * 5 * 8;
    const short* bp2 = bp0 + 32 * 5 * 8;
    const short* bp3 = bp0 + 48 * 5 * 8;

    const int srow = t >> 2;
    const int sseg = t & 3;
    short* sa0 = lds_a + (srow * 5 + sseg) * 8;
    short* sa1 = lds_a + ((srow + 64) * 5 + sseg) * 8;
    short* sb  = lds_b + (srow * 5 + sseg) * 8;
    const bool ok0 = (bm + srow) < M;
    const bool ok1 = (bm + 64 + srow) < M;
    const bf16* gA0 = A + (size_t)(bm + srow) * K + sseg * 8;
    const bf16* gA1 = A + (size_t)(bm + 64 + srow) * K + sseg * 8;
    const bf16* gB  = Bt + (size_t)(bn + srow) * K + sseg * 8;

    f32x4 acc[2][4];
    #pragma unroll
    for (int i = 0; i < 2; ++i)
        #pragma unroll
        for (int j = 0; j < 4; ++j) acc[i][j] = (f32x4){0.f, 0.f, 0.f, 0.f};

    uint4 av0 = {0u, 0u, 0u, 0u}, av1 = {0u, 0u, 0u, 0u};
    if (ok0) av0 = *(const uint4*)gA0;
    if (ok1) av1 = *(const uint4*)gA1;
    uint4 bv = *(const uint4*)gB;

    for (int k0 = 0; k0 < K; k0 += 32) {
        __syncthreads();
        *(uint4*)sa0 = av0;
        *(uint4*)sa1 = av1;
        *(uint4*)sb  = bv;
        __syncthreads();
        if (k0 + 32 < K) {
            if (ok0) av0 = *(const uint4*)(gA0 + k0 + 32);
            if (ok1) av1 = *(const uint4*)(gA1 + k0 + 32);
            bv = *(const uint4*)(gB + k0 + 32);
        }
        const bf16x8 a0 = *(const bf16x8*)ap0;
        const bf16x8 a1 = *(const bf16x8*)ap1;
        const bf16x8 b0 = *(const bf16x8*)bp0;
        const bf16x8 b1 = *(const bf16x8*)bp1;
        const bf16x8 b2 = *(const bf16x8*)bp2;
        const bf16x8 b3 = *(const bf16x8*)bp3;
        acc[0][0] = __builtin_amdgcn_mfma_f32_16x16x32_bf16(a0, b0, acc[0][0], 0, 0, 0);
        acc[0][1] = __builtin_amdgcn_mfma_f32_16x16x32_bf16(a0, b1, acc[0][1], 0, 0, 0);
        acc[0][2] = __builtin_amdgcn_mfma_f32_16x16x32_bf16(a0, b2, acc[0][2], 0, 0, 0);
        acc[0][3] = __builtin_amdgcn_mfma_f32_16x16x32_bf16(a0, b3, acc[0][3], 0, 0, 0);
        acc[1][0] = __builtin_amdgcn_mfma_f32_16x16x32_bf16(a1, b0, acc[1][0], 0, 0, 0);
        acc[1][1] = __builtin_amdgcn_mfma_f32_16x16x32_bf16(a1, b1, acc[1][1], 0, 0, 0);
        acc[1][2] = __builtin_amdgcn_mfma_f32_16x16x32_bf16(a1, b2, acc[1][2], 0, 0, 0);
        acc[1][3] = __builtin_amdgcn_mfma_f32_16x16x32_bf16(a1, b3, acc[1][3], 0, 0, 0);
    }

    // fused attention dots (layer 2: single head)
    float wsv[4], wdv[4];
    #pragma unroll
    for (int j = 0; j < 4; ++j) {
        wsv[j] = ws_[bn + j * 16 + fm];
        wdv[j] = wd_[bn + j * 16 + fm];
    }
    #pragma unroll
    for (int i = 0; i < 2; ++i) {
        const int rb = bm + wv * 32 + i * 16 + fq * 4;
        #pragma unroll
        for (int r = 0; r < 4; ++r) {
            const int row = rb + r;
            float ps = 0.f, pd = 0.f;
            #pragma unroll
            for (int j = 0; j < 4; ++j) {
                const float av = acc[i][j][r];
                ps += av * wsv[j];
                pd += av * wdv[j];
            }
            #pragma unroll
            for (int o = 8; o > 0; o >>= 1) {
                ps += __shfl_xor(ps, o);
                pd += __shfl_xor(pd, o);
            }
            if (row < M) {
                if (fm == 0) {
                    atomicAdd(&a_s[row], ps);
                    atomicAdd(&a_d[row], pd);
                }
                #pragma unroll
                for (int j = 0; j < 4; ++j)
                    C[(size_t)row * N + bn + j * 16 + fm] = __float2bfloat16(acc[i][j][r]);
            }
        }
    }
}

// ------- MFMA NT GEMM 128x128 (r17 reg-dbuf staging, proven) + fused att dots (r24) -
// Block's 128 cols lie in exactly one head (bn % 256 in {0,128}).
__global__ __launch_bounds__(256) void gemm_mfma128(const bf16* __restrict__ A,
                                                    const bf16* __restrict__ Bt,
                                                    bf16* __restrict__ C,
                                                    const float* __restrict__ ws_,
                                                    const float* __restrict__ wd_,
                                                    float* __restrict__ a_s,
                                                    float* __restrict__ a_d,
                                                    int M, int N, int K) {
    __shared__ short lds_a[128 * 5 * 8];   // 10 KB
    __shared__ short lds_b[128 * 5 * 8];   // 10 KB
    const int bm = blockIdx.y * 128;
    const int bn = blockIdx.x * 128;
    const int t = threadIdx.x;
    const int lane = t & 63;
    const int wv = t >> 6;                 // wave -> rows [wv*32, wv*32+32)
    const int fm = lane & 15;
    const int fq = lane >> 4;

    const short* ap0 = lds_a + ((wv * 32 + fm) * 5 + fq) * 8;
    const short* ap1 = ap0 + 16 * 5 * 8;

    const int srow = t >> 2;               // 0..63
    const int sseg = t & 3;
    short* sa0 = lds_a + (srow * 5 + sseg) * 8;
    short* sa1 = lds_a + ((srow + 64) * 5 + sseg) * 8;
    short* sb0 = lds_b + (srow * 5 + sseg) * 8;
    short* sb1 = lds_b + ((srow + 64) * 5 + sseg) * 8;
    const bool ok0 = (bm + srow) < M;
    const bool ok1 = (bm + 64 + srow) < M;
    const bf16* gA0 = A + (size_t)(bm + srow) * K + sseg * 8;
    const bf16* gA1 = A + (size_t)(bm + 64 + srow) * K + sseg * 8;
    const bf16* gB0 = Bt + (size_t)(bn + srow) * K + sseg * 8;
    const bf16* gB1 = Bt + (size_t)(bn + 64 + srow) * K + sseg * 8;

    f32x4 acc[2][8];
    #pragma unroll
    for (int i = 0; i < 2; ++i)
        #pragma unroll
        for (int j = 0; j < 8; ++j) acc[i][j] = (f32x4){0.f, 0.f, 0.f, 0.f};

    uint4 av0 = {0u, 0u, 0u, 0u}, av1 = {0u, 0u, 0u, 0u};
    if (ok0) av0 = *(const uint4*)gA0;
    if (ok1) av1 = *(const uint4*)gA1;
    uint4 bv0 = *(const uint4*)gB0;
    uint4 bv1 = *(const uint4*)gB1;

    for (int k0 = 0; k0 < K; k0 += 32) {
        __syncthreads();
        *(uint4*)sa0 = av0;
        *(uint4*)sa1 = av1;
        *(uint4*)sb0 = bv0;
        *(uint4*)sb1 = bv1;
        __syncthreads();
        if (k0 + 32 < K) {
            if (ok0) av0 = *(const uint4*)(gA0 + k0 + 32);
            if (ok1) av1 = *(const uint4*)(gA1 + k0 + 32);
            bv0 = *(const uint4*)(gB0 + k0 + 32);
            bv1 = *(const uint4*)(gB1 + k0 + 32);
        }
        const bf16x8 a0 = *(const bf16x8*)ap0;
        const bf16x8 a1 = *(const bf16x8*)ap1;
        #pragma unroll
        for (int j = 0; j < 8; ++j) {
            const bf16x8 bj = *(const bf16x8*)(lds_b + ((j * 16 + fm) * 5 + fq) * 8);
            acc[0][j] = __builtin_amdgcn_mfma_f32_16x16x32_bf16(a0, bj, acc[0][j], 0, 0, 0);
            acc[1][j] = __builtin_amdgcn_mfma_f32_16x16x32_bf16(a1, bj, acc[1][j], 0, 0, 0);
        }
    }

    // fused attention dots: cols of this block are head hd; partial dot per row.
    const int hd = bn >> 8;
    const int cb = (bn & 255) + fm;
    float wsv[8], wdv[8];
    #pragma unroll
    for (int j = 0; j < 8; ++j) {
        wsv[j] = ws_[hd * 256 + cb + j * 16];
        wdv[j] = wd_[hd * 256 + cb + j * 16];
    }
    #pragma unroll
    for (int i = 0; i < 2; ++i) {
        const int rb = bm + wv * 32 + i * 16 + fq * 4;
        #pragma unroll
        for (int r = 0; r < 4; ++r) {
            const int row = rb + r;
            float ps = 0.f, pd = 0.f;
            #pragma unroll
            for (int j = 0; j < 8; ++j) {
                const float av = acc[i][j][r];
                ps += av * wsv[j];
                pd += av * wdv[j];
            }
            #pragma unroll
            for (int o = 8; o > 0; o >>= 1) {
                ps += __shfl_xor(ps, o);
                pd += __shfl_xor(pd, o);
            }
            if (row < M) {
                if (fm == 0) {
                    atomicAdd(&a_s[row * HEADS + hd], ps);
                    atomicAdd(&a_d[row * HEADS + hd], pd);
                }
                #pragma unroll
                for (int j = 0; j < 8; ++j)
                    C[(size_t)row * N + bn + j * 16 + fm] = __float2bfloat16(acc[i][j][r]);
            }
        }
    }
}

// ---------------- layer 1: XCD-sliced gather (r25) ----------------------------------
// Each wave handles ONE node x ONE 128-channel slice (256B/row). Grid = quads x 8
// slices with slice = blockIdx % 8 -> round-robin block->XCD dispatch pins slice j to
// XCD j; per-XCD L2 footprint = 10000 x 256B = 2.56MB < 4MB L2. Kills the 8x L2-fill
// multiplication (FETCH 133MB -> ~h1 size). Slice lies in one head -> 1-head softmax.
__global__ __launch_bounds__(256) void gat_gather1(
    const int* __restrict__ offs, const int* __restrict__ nbr,
    const bf16* __restrict__ h1, const float* __restrict__ a_s, const float* __restrict__ a_d,
    const float* __restrict__ bias, bf16* __restrict__ outp)
{
    const int lane = threadIdx.x & 63;
    const int wave = threadIdx.x >> 6;
    const int sl = blockIdx.x & 7;            // slice -> XCD (round-robin heuristic)
    const int n  = (blockIdx.x >> 3) * 4 + wave;
    const int hd = sl >> 1;                   // slice's head
    const int chb = sl * 128;                 // slice channel base
    const int beg = offs[n];
    const int deg = offs[n + 1] - beg;

    float acc0 = 0.f, acc1 = 0.f;
    const bf16* hsl = h1 + chb + lane * 2;    // my 2 channels of the slice

    // gather cnt edges; 8 edges unrolled => 8 independent 4B loads in flight/lane.
    auto gshfl = [&](int cnt, int sv, float alv) {
        for (int k0 = 0; k0 < cnt; k0 += 8) {
            unsigned qv[8];
            float av[8];
            #pragma unroll
            for (int u = 0; u < 8; ++u) {
                const int k = k0 + u;
                if (k < cnt) {                 // wave-uniform branch
                    const int sk = __shfl(sv, k);
                    av[u] = __shfl(alv, k);
                    qv[u] = *(const unsigned*)(hsl + (size_t)sk * H1DIM);
                } else {
                    qv[u] = 0u;
                    av[u] = 0.f;
                }
            }
            #pragma unroll
            for (int u = 0; u < 8; ++u) {
                acc0 += lo2f(qv[u]) * av[u];
                acc1 += hi2f(qv[u]) * av[u];
            }
        }
    };

    if (deg > 0) {
        const float adn = a_d[n * HEADS + hd];
        if (deg <= 64) {
            // single pass: lane k owns edge k; 1-head softmax via shuffles
            const bool act = lane < deg;
            int s = 0;
            float v = -INFINITY;
            if (act) {
                s = nbr[beg + lane];
                float t = a_s[s * HEADS + hd] + adn;
                v = t > 0.f ? t : NEG_SLOPE * t;
            }
            float m = v;
            #pragma unroll
            for (int o = 32; o > 0; o >>= 1) m = fmaxf(m, __shfl_xor(m, o));
            const float ex = act ? __expf(v - m) : 0.f;
            float sm = ex;
            #pragma unroll
            for (int o = 32; o > 0; o >>= 1) sm += __shfl_xor(sm, o);
            const float al = ex / (sm + 1e-16f);
            gshfl(deg, s, al);
        } else {
            // rare path (deg > 64): in-wave 3-pass streaming softmax, chunked gather
            float m = -INFINITY;
            for (int k = lane; k < deg; k += 64) {
                const int s = nbr[beg + k];
                float t = a_s[s * HEADS + hd] + adn;
                t = t > 0.f ? t : NEG_SLOPE * t;
                m = fmaxf(m, t);
            }
            #pragma unroll
            for (int o = 32; o > 0; o >>= 1) m = fmaxf(m, __shfl_xor(m, o));
            float q = 0.f;
            for (int k = lane; k < deg; k += 64) {
                const int s = nbr[beg + k];
                float t = a_s[s * HEADS + hd] + adn;
                t = t > 0.f ? t : NEG_SLOPE * t;
                q += __expf(t - m);
            }
            #pragma unroll
            for (int o = 32; o > 0; o >>= 1) q += __shfl_xor(q, o);
            const float den = q + 1e-16f;
            for (int bs = 0; bs < deg; bs += 64) {
                const int cnt = min(64, deg - bs);
                int s = 0;
                float al = 0.f;
                if (lane < cnt) {
                    s = nbr[beg + bs + lane];
                    float t = a_s[s * HEADS + hd] + adn;
                    t = t > 0.f ? t : NEG_SLOPE * t;
                    al = __expf(t - m) / den;
                }
                gshfl(cnt, s, al);
            }
        }
    }

    // epilogue: bias + ELU + 2x bf16 nt store (4B)
    const int ch = chb + lane * 2;
    const float2 bv = *(const float2*)(bias + ch);
    float w0 = acc0 + bv.x;
    float w1 = acc1 + bv.y;
    w0 = w0 > 0.f ? w0 : (__expf(w0) - 1.f);
    w1 = w1 > 0.f ? w1 : (__expf(w1) - 1.f);
    bf16 o0 = __float2bfloat16(w0), o1 = __float2bfloat16(w1);
    const unsigned ob = ((unsigned)(*(unsigned short*)&o1) << 16) | (*(unsigned short*)&o0);
    __builtin_nontemporal_store(ob, (unsigned*)(outp + (size_t)n * H1DIM + ch));
}

// ---------------- layer 2: wave-per-node softmax + gather (r19), fp32 nt out --------
__global__ __launch_bounds__(256) void gat_gather2(
    const int* __restrict__ offs, const int* __restrict__ nbr,
    const bf16* __restrict__ h2, const float* __restrict__ a_s, const float* __restrict__ a_d,
    const float* __restrict__ bias, float* __restrict__ outp)
{
    const int lane = threadIdx.x & 63;
    const int wave = threadIdx.x >> 6;
    const int n = blockIdx.x * 4 + wave;
    const int beg = offs[n];
    const int deg = offs[n + 1] - beg;

    float acc[4] = {0.f, 0.f, 0.f, 0.f};

    // gather cnt edges; 8 edges unrolled => 8 independent 8B loads in flight.
    auto gshfl = [&](int cnt, int sv, float alv) {
        for (int k0 = 0; k0 < cnt; k0 += 8) {
            uint2 q[8];
            float av[8];
            #pragma unroll
            for (int u = 0; u < 8; ++u) {
                const int k = k0 + u;
                if (k < cnt) {                        // wave-uniform branch
                    const int sk = __shfl(sv, k);
                    av[u] = __shfl(alv, k);
                    q[u] = *(const uint2*)(h2 + (size_t)sk * OUT_C + lane * 4);
                } else {
                    q[u] = (uint2){0u, 0u};
                    av[u] = 0.f;
                }
            }
            #pragma unroll
            for (int u = 0; u < 8; ++u) {
                acc[0] += lo2f(q[u].x) * av[u]; acc[1] += hi2f(q[u].x) * av[u];
                acc[2] += lo2f(q[u].y) * av[u]; acc[3] += hi2f(q[u].y) * av[u];
            }
        }
    };

    if (deg > 0) {
        const float adn = a_d[n];
        if (deg <= 64) {
            const bool act = lane < deg;
            int s = 0;
            float v = -INFINITY;
            if (act) {
                s = nbr[beg + lane];
                float t = a_s[s] + adn;
                v = t > 0.f ? t : NEG_SLOPE * t;
            }
            float m = v;
            #pragma unroll
            for (int o = 32; o > 0; o >>= 1) m = fmaxf(m, __shfl_xor(m, o));
            const float ex = act ? __expf(v - m) : 0.f;
            float sm = ex;
            #pragma unroll
            for (int o = 32; o > 0; o >>= 1) sm += __shfl_xor(sm, o);
            const float al = ex / (sm + 1e-16f);
            gshfl(deg, s, al);
        } else {
            float m = -INFINITY;
            for (int k = lane; k < deg; k += 64) {
                const int s = nbr[beg + k];
                float t = a_s[s] + adn;
                t = t > 0.f ? t : NEG_SLOPE * t;
                m = fmaxf(m, t);
            }
            #pragma unroll
            for (int o = 32; o > 0; o >>= 1) m = fmaxf(m, __shfl_xor(m, o));
            float q = 0.f;
            for (int k = lane; k < deg; k += 64) {
                const int s = nbr[beg + k];
                float t = a_s[s] + adn;
                t = t > 0.f ? t : NEG_SLOPE * t;
                q += __expf(t - m);
            }
            #pragma unroll
            for (int o = 32; o > 0; o >>= 1) q += __shfl_xor(q, o);
            const float den = q + 1e-16f;
            for (int bs = 0; bs < deg; bs += 64) {
                const int cnt = min(64, deg - bs);
                int s = 0;
                float al = 0.f;
                if (lane < cnt) {
                    s = nbr[beg + bs + lane];
                    float t = a_s[s] + adn;
                    t = t > 0.f ? t : NEG_SLOPE * t;
                    al = __expf(t - m) / den;
                }
                gshfl(cnt, s, al);
            }
        }
    }

    const int ch = lane * 4;
    const float4 bv = *(const float4*)(bias + ch);
    f32x4 w;
    w[0] = acc[0] + bv.x; w[1] = acc[1] + bv.y;
    w[2] = acc[2] + bv.z; w[3] = acc[3] + bv.w;
    __builtin_nontemporal_store(w, (f32x4*)(outp + (size_t)n * OUT_C + ch));
}

extern "C" void kernel_launch(void* const* d_in, const int* in_sizes, int n_in,
                              void* d_out, int out_size, void* d_ws, size_t ws_size,
                              hipStream_t stream) {
    (void)in_sizes; (void)n_in; (void)out_size; (void)ws_size;
    const float* x        = (const float*)d_in[0];
    const int*   ei       = (const int*)d_in[1];   // int32 [2,E] (verified round 4)
    const float* W1       = (const float*)d_in[2];
    const float* att_src1 = (const float*)d_in[3];
    const float* att_dst1 = (const float*)d_in[4];
    const float* b1       = (const float*)d_in[5];
    const float* W2       = (const float*)d_in[6];
    const float* att_src2 = (const float*)d_in[7];
    const float* att_dst2 = (const float*)d_in[8];
    const float* b2       = (const float*)d_in[9];
    float* out = (float*)d_out;

    // ---- workspace carve (all 256B-aligned) ----
    char* base = (char*)d_ws;
    size_t woff = 0;
    auto carve = [&](size_t bytes) -> char* {
        char* p = base + woff;
        woff += (bytes + 255) & ~(size_t)255;
        return p;
    };
    bf16* h1   = (bf16*)carve((size_t)N_NODES * H1DIM * 2);   // 20.48 MB
    bf16* a2   = (bf16*)carve((size_t)N_NODES * H1DIM * 2);   // 20.48 MB
    bf16* h2   = (bf16*)carve((size_t)N_NODES * OUT_C * 2);   //  5.12 MB
    bf16* xb   = (bf16*)carve((size_t)N_NODES * IN_C * 2);    // 15.36 MB
    bf16* W1t  = (bf16*)carve((size_t)H1DIM * IN_C * 2);
    bf16* W2t  = (bf16*)carve((size_t)OUT_C * H1DIM * 2);
    // NOTE: as1..degs must stay CONTIGUOUS — prep_kernel zeroes the whole span.
    // Zeroing is REQUIRED for the fused-atomic att dots (as1/ad1/as2/ad2 accumulate).
    float* as1 = (float*)carve((size_t)N_NODES * HEADS * 4);  // 160000 B
    float* ad1 = (float*)carve((size_t)N_NODES * HEADS * 4);  // 160000 B
    float* as2 = (float*)carve((size_t)N_NODES * 4);          // 40000 -> 40192 B
    float* ad2 = (float*)carve((size_t)N_NODES * 4);          // 40000 -> 40192 B
    int* degs  = (int*)carve((size_t)4 * N_NODES * 4);        // 160000 B
    int* deg_d = degs;
    int* deg_s = degs + N_NODES;
    int* cur_d = degs + 2 * N_NODES;
    int* cur_s = degs + 3 * N_NODES;
    int* offs_d = (int*)carve((size_t)(N_NODES + 1) * 4);
    int* offs_s = (int*)carve((size_t)(N_NODES + 1) * 4);
    int* nbr_d  = (int*)carve((size_t)N_EDGES * 4);
    int* nbr_s  = (int*)carve((size_t)N_EDGES * 4);

    // ---- fused prep: cvt + transposes + zero(as1..degs) ----
    prep_kernel<<<CVT_BLOCKS + T1_BLOCKS + T2_BLOCKS + Z_BLOCKS, 256, 0, stream>>>(
        x, xb, W1, W1t, W2, W2t, (int*)as1);

    // ---- CSR build ----
    count_deg<<<(N_EDGES + 255) / 256, 256, 0, stream>>>(ei, deg_d, deg_s);
    scan_fast2<<<2, 1024, 0, stream>>>(deg_d, offs_d, deg_s, offs_s, N_NODES);
    fill_csr<<<(N_EDGES + 255) / 256, 256, 0, stream>>>(ei, offs_d, offs_s, cur_d, cur_s, nbr_d, nbr_s);

    // ---- layer 1: GEMM with fused att dots, then XCD-sliced gather ----
    gemm_mfma128<<<dim3(H1DIM / 128, (N_NODES + 127) / 128), 256, 0, stream>>>(
        xb, W1t, h1, att_src1, att_dst1, as1, ad1, N_NODES, H1DIM, IN_C);
    gat_gather1<<<(N_NODES / 4) * 8, 256, 0, stream>>>(offs_d, nbr_d, h1, as1, ad1, b1, a2);

    // ---- layer 2: GEMM with fused att dots, then gather ----
    gemm_mfma64<<<dim3(OUT_C / 64, (N_NODES + 127) / 128), 256, 0, stream>>>(
        a2, W2t, h2, att_src2, att_dst2, as2, ad2, N_NODES, OUT_C, H1DIM);
    gat_gather2<<<N_NODES / 4, 256, 0, stream>>>(offs_s, nbr_s, h2, as2, ad2, b2, out);
}

// Round 11
// 255.564 us; speedup vs baseline: 1.0270x; 1.0270x over previous
//
#include <hip/hip_runtime.h>
#include <hip/hip_bf16.h>
#include <math.h>

typedef __hip_bfloat16 bf16;
typedef __attribute__((ext_vector_type(8))) short bf16x8;
typedef __attribute__((ext_vector_type(4))) float f32x4;
typedef __attribute__((ext_vector_type(4))) unsigned int u32x4;

#define N_NODES 10000
#define N_EDGES 160000
#define IN_C    768
#define H1DIM   1024      // HEADS * HID
#define HEADS   4
#define OUT_C   256
#define NEG_SLOPE 0.2f

__device__ __forceinline__ float u2f(unsigned short u) { return __uint_as_float(((unsigned)u) << 16); }
__device__ __forceinline__ float lo2f(unsigned u) { return __uint_as_float(u << 16); }
__device__ __forceinline__ float hi2f(unsigned u) { return __uint_as_float(u & 0xFFFF0000u); }

// ---------------- fused prep: cvt x->bf16, transpose W1/W2, zero (r15 proven) -------
#define CVT_BLOCKS 7500                    // 10000*768/4 / 256  (exact)
#define T1_BLOCKS  768                     // (1024/32) x (768/32)
#define T2_BLOCKS  256                     // (256/32) x (1024/32)
#define Z_WORDS    140096                  // as1+ad1+as2+ad2+degs span (with carve pads)/4
#define Z_BLOCKS   548                     // ceil(Z_WORDS/256)

__global__ __launch_bounds__(256) void prep_kernel(
    const float* __restrict__ x, bf16* __restrict__ xb,
    const float* __restrict__ W1, bf16* __restrict__ W1t,
    const float* __restrict__ W2, bf16* __restrict__ W2t,
    int* __restrict__ zbase)
{
    __shared__ float tile[32][33];
    const int bid = blockIdx.x;
    const int tid = threadIdx.x;
    if (bid < CVT_BLOCKS) {
        const int i = bid * 256 + tid;
        const float4 v = *((const float4*)x + i);
        bf16* d = xb + (size_t)i * 4;
        d[0] = __float2bfloat16(v.x); d[1] = __float2bfloat16(v.y);
        d[2] = __float2bfloat16(v.z); d[3] = __float2bfloat16(v.w);
        return;
    }
    if (bid < CVT_BLOCKS + T1_BLOCKS + T2_BLOCKS) {
        const bool isW1 = bid < CVT_BLOCKS + T1_BLOCKS;
        const int lb = isW1 ? (bid - CVT_BLOCKS) : (bid - CVT_BLOCKS - T1_BLOCKS);
        const int TX = isW1 ? (H1DIM / 32) : (OUT_C / 32);
        const int R  = isW1 ? IN_C : H1DIM;      // src rows
        const int C  = isW1 ? H1DIM : OUT_C;     // src cols
        const float* src = isW1 ? W1 : W2;
        bf16* dst = isW1 ? W1t : W2t;
        const int bc = (lb % TX) * 32;
        const int br = (lb / TX) * 32;
        const int tx = tid & 31, ty = tid >> 5;
        #pragma unroll
        for (int i = ty; i < 32; i += 8)
            tile[i][tx] = src[(size_t)(br + i) * C + bc + tx];
        __syncthreads();
        #pragma unroll
        for (int i = ty; i < 32; i += 8)
            dst[(size_t)(bc + i) * R + br + tx] = __float2bfloat16(tile[tx][i]);
        return;
    }
    const int i = (bid - CVT_BLOCKS - T1_BLOCKS - T2_BLOCKS) * 256 + tid;
    if (i < Z_WORDS) zbase[i] = 0;
}

// ---------------- CSR build ----------------
__global__ void count_deg(const int* __restrict__ ei, int* __restrict__ deg_d, int* __restrict__ deg_s) {
    const int e = blockIdx.x * blockDim.x + threadIdx.x;
    if (e >= N_EDGES) return;
    atomicAdd(&deg_d[ei[N_EDGES + e]], 1);
    atomicAdd(&deg_s[ei[e]], 1);
}

__global__ __launch_bounds__(1024) void scan_fast2(const int* __restrict__ deg_d, int* __restrict__ offs_d,
                                                   const int* __restrict__ deg_s, int* __restrict__ offs_s,
                                                   int n) {
    const int* deg = blockIdx.x ? deg_s : deg_d;
    int* offs      = blockIdx.x ? offs_s : offs_d;
    const int t = threadIdx.x;
    const int iter = (n + 1023) >> 10;
    const int base = t * iter;
    int ex[16];
    int sum = 0;
    for (int j = 0; j < iter; ++j) {
        const int i = base + j;
        const int v = (i < n) ? deg[i] : 0;
        ex[j] = sum;
        sum += v;
    }
    const int lane = t & 63, w = t >> 6;
    int inc = sum;
    #pragma unroll
    for (int o = 1; o < 64; o <<= 1) {
        const int x = __shfl_up(inc, o);
        if (lane >= o) inc += x;
    }
    __shared__ int wtot[16];
    if (lane == 63) wtot[w] = inc;
    __syncthreads();
    if (t == 0) {
        int c = 0;
        #pragma unroll
        for (int i = 0; i < 16; ++i) { const int x = wtot[i]; wtot[i] = c; c += x; }
    }
    __syncthreads();
    const int tbase = wtot[w] + inc - sum;
    for (int j = 0; j < iter; ++j) {
        const int i = base + j;
        if (i < n) offs[i] = tbase + ex[j];
    }
    if (t == 1023) offs[n] = tbase + sum;
}

// stores NEIGHBOR NODE id directly (r20): dst-CSR holds src node, src-CSR holds dst node
__global__ void fill_csr(const int* __restrict__ ei,
                         const int* __restrict__ offs_d, const int* __restrict__ offs_s,
                         int* __restrict__ cur_d, int* __restrict__ cur_s,
                         int* __restrict__ nbr_d, int* __restrict__ nbr_s) {
    const int e = blockIdx.x * blockDim.x + threadIdx.x;
    if (e >= N_EDGES) return;
    const int s = ei[e];
    const int d = ei[N_EDGES + e];
    const int p = atomicAdd(&cur_d[d], 1);
    nbr_d[offs_d[d] + p] = s;
    const int q = atomicAdd(&cur_s[s], 1);
    nbr_s[offs_s[s] + q] = d;
}

// ------- MFMA NT GEMM 128x64 (r15 reg-dbuf staging, proven) + fused att dots (r24) --
__global__ __launch_bounds__(256) void gemm_mfma64(const bf16* __restrict__ A,
                                                   const bf16* __restrict__ Bt,
                                                   bf16* __restrict__ C,
                                                   const float* __restrict__ ws_,
                                                   const float* __restrict__ wd_,
                                                   float* __restrict__ a_s,
                                                   float* __restrict__ a_d,
                                                   int M, int N, int K) {
    __shared__ short lds_a[128 * 5 * 8];
    __shared__ short lds_b[64 * 5 * 8];
    const int bm = blockIdx.y * 128;
    const int bn = blockIdx.x * 64;
    const int t = threadIdx.x;
    const int lane = t & 63;
    const int wv = t >> 6;
    const int fm = lane & 15;
    const int fq = lane >> 4;

    const short* ap0 = lds_a + ((wv * 32 + fm) * 5 + fq) * 8;
    const short* ap1 = ap0 + 16 * 5 * 8;
    const short* bp0 = lds_b + ((fm) * 5 + fq) * 8;
    const short* bp1 = bp0 + 16 * 5 * 8;
    const short* bp2 = bp0 + 32 * 5 * 8;
    const short* bp3 = bp0 + 48 * 5 * 8;

    const int srow = t >> 2;
    const int sseg = t & 3;
    short* sa0 = lds_a + (srow * 5 + sseg) * 8;
    short* sa1 = lds_a + ((srow + 64) * 5 + sseg) * 8;
    short* sb  = lds_b + (srow * 5 + sseg) * 8;
    const bool ok0 = (bm + srow) < M;
    const bool ok1 = (bm + 64 + srow) < M;
    const bf16* gA0 = A + (size_t)(bm + srow) * K + sseg * 8;
    const bf16* gA1 = A + (size_t)(bm + 64 + srow) * K + sseg * 8;
    const bf16* gB  = Bt + (size_t)(bn + srow) * K + sseg * 8;

    f32x4 acc[2][4];
    #pragma unroll
    for (int i = 0; i < 2; ++i)
        #pragma unroll
        for (int j = 0; j < 4; ++j) acc[i][j] = (f32x4){0.f, 0.f, 0.f, 0.f};

    uint4 av0 = {0u, 0u, 0u, 0u}, av1 = {0u, 0u, 0u, 0u};
    if (ok0) av0 = *(const uint4*)gA0;
    if (ok1) av1 = *(const uint4*)gA1;
    uint4 bv = *(const uint4*)gB;

    for (int k0 = 0; k0 < K; k0 += 32) {
        __syncthreads();
        *(uint4*)sa0 = av0;
        *(uint4*)sa1 = av1;
        *(uint4*)sb  = bv;
        __syncthreads();
        if (k0 + 32 < K) {
            if (ok0) av0 = *(const uint4*)(gA0 + k0 + 32);
            if (ok1) av1 = *(const uint4*)(gA1 + k0 + 32);
            bv = *(const uint4*)(gB + k0 + 32);
        }
        const bf16x8 a0 = *(const bf16x8*)ap0;
        const bf16x8 a1 = *(const bf16x8*)ap1;
        const bf16x8 b0 = *(const bf16x8*)bp0;
        const bf16x8 b1 = *(const bf16x8*)bp1;
        const bf16x8 b2 = *(const bf16x8*)bp2;
        const bf16x8 b3 = *(const bf16x8*)bp3;
        acc[0][0] = __builtin_amdgcn_mfma_f32_16x16x32_bf16(a0, b0, acc[0][0], 0, 0, 0);
        acc[0][1] = __builtin_amdgcn_mfma_f32_16x16x32_bf16(a0, b1, acc[0][1], 0, 0, 0);
        acc[0][2] = __builtin_amdgcn_mfma_f32_16x16x32_bf16(a0, b2, acc[0][2], 0, 0, 0);
        acc[0][3] = __builtin_amdgcn_mfma_f32_16x16x32_bf16(a0, b3, acc[0][3], 0, 0, 0);
        acc[1][0] = __builtin_amdgcn_mfma_f32_16x16x32_bf16(a1, b0, acc[1][0], 0, 0, 0);
        acc[1][1] = __builtin_amdgcn_mfma_f32_16x16x32_bf16(a1, b1, acc[1][1], 0, 0, 0);
        acc[1][2] = __builtin_amdgcn_mfma_f32_16x16x32_bf16(a1, b2, acc[1][2], 0, 0, 0);
        acc[1][3] = __builtin_amdgcn_mfma_f32_16x16x32_bf16(a1, b3, acc[1][3], 0, 0, 0);
    }

    // fused attention dots (layer 2: single head)
    float wsv[4], wdv[4];
    #pragma unroll
    for (int j = 0; j < 4; ++j) {
        wsv[j] = ws_[bn + j * 16 + fm];
        wdv[j] = wd_[bn + j * 16 + fm];
    }
    #pragma unroll
    for (int i = 0; i < 2; ++i) {
        const int rb = bm + wv * 32 + i * 16 + fq * 4;
        #pragma unroll
        for (int r = 0; r < 4; ++r) {
            const int row = rb + r;
            float ps = 0.f, pd = 0.f;
            #pragma unroll
            for (int j = 0; j < 4; ++j) {
                const float av = acc[i][j][r];
                ps += av * wsv[j];
                pd += av * wdv[j];
            }
            #pragma unroll
            for (int o = 8; o > 0; o >>= 1) {
                ps += __shfl_xor(ps, o);
                pd += __shfl_xor(pd, o);
            }
            if (row < M) {
                if (fm == 0) {
                    atomicAdd(&a_s[row], ps);
                    atomicAdd(&a_d[row], pd);
                }
                #pragma unroll
                for (int j = 0; j < 4; ++j)
                    C[(size_t)row * N + bn + j * 16 + fm] = __float2bfloat16(acc[i][j][r]);
            }
        }
    }
}

// ------- MFMA NT GEMM 128x128 (r17 reg-dbuf staging, proven) + fused att dots (r24) -
// Block's 128 cols lie in exactly one head (bn % 256 in {0,128}).
__global__ __launch_bounds__(256) void gemm_mfma128(const bf16* __restrict__ A,
                                                    const bf16* __restrict__ Bt,
                                                    bf16* __restrict__ C,
                                                    const float* __restrict__ ws_,
                                                    const float* __restrict__ wd_,
                                                    float* __restrict__ a_s,
                                                    float* __restrict__ a_d,
                                                    int M, int N, int K) {
    __shared__ short lds_a[128 * 5 * 8];   // 10 KB
    __shared__ short lds_b[128 * 5 * 8];   // 10 KB
    const int bm = blockIdx.y * 128;
    const int bn = blockIdx.x * 128;
    const int t = threadIdx.x;
    const int lane = t & 63;
    const int wv = t >> 6;                 // wave -> rows [wv*32, wv*32+32)
    const int fm = lane & 15;
    const int fq = lane >> 4;

    const short* ap0 = lds_a + ((wv * 32 + fm) * 5 + fq) * 8;
    const short* ap1 = ap0 + 16 * 5 * 8;

    const int srow = t >> 2;               // 0..63
    const int sseg = t & 3;
    short* sa0 = lds_a + (srow * 5 + sseg) * 8;
    short* sa1 = lds_a + ((srow + 64) * 5 + sseg) * 8;
    short* sb0 = lds_b + (srow * 5 + sseg) * 8;
    short* sb1 = lds_b + ((srow + 64) * 5 + sseg) * 8;
    const bool ok0 = (bm + srow) < M;
    const bool ok1 = (bm + 64 + srow) < M;
    const bf16* gA0 = A + (size_t)(bm + srow) * K + sseg * 8;
    const bf16* gA1 = A + (size_t)(bm + 64 + srow) * K + sseg * 8;
    const bf16* gB0 = Bt + (size_t)(bn + srow) * K + sseg * 8;
    const bf16* gB1 = Bt + (size_t)(bn + 64 + srow) * K + sseg * 8;

    f32x4 acc[2][8];
    #pragma unroll
    for (int i = 0; i < 2; ++i)
        #pragma unroll
        for (int j = 0; j < 8; ++j) acc[i][j] = (f32x4){0.f, 0.f, 0.f, 0.f};

    uint4 av0 = {0u, 0u, 0u, 0u}, av1 = {0u, 0u, 0u, 0u};
    if (ok0) av0 = *(const uint4*)gA0;
    if (ok1) av1 = *(const uint4*)gA1;
    uint4 bv0 = *(const uint4*)gB0;
    uint4 bv1 = *(const uint4*)gB1;

    for (int k0 = 0; k0 < K; k0 += 32) {
        __syncthreads();
        *(uint4*)sa0 = av0;
        *(uint4*)sa1 = av1;
        *(uint4*)sb0 = bv0;
        *(uint4*)sb1 = bv1;
        __syncthreads();
        if (k0 + 32 < K) {
            if (ok0) av0 = *(const uint4*)(gA0 + k0 + 32);
            if (ok1) av1 = *(const uint4*)(gA1 + k0 + 32);
            bv0 = *(const uint4*)(gB0 + k0 + 32);
            bv1 = *(const uint4*)(gB1 + k0 + 32);
        }
        const bf16x8 a0 = *(const bf16x8*)ap0;
        const bf16x8 a1 = *(const bf16x8*)ap1;
        #pragma unroll
        for (int j = 0; j < 8; ++j) {
            const bf16x8 bj = *(const bf16x8*)(lds_b + ((j * 16 + fm) * 5 + fq) * 8);
            acc[0][j] = __builtin_amdgcn_mfma_f32_16x16x32_bf16(a0, bj, acc[0][j], 0, 0, 0);
            acc[1][j] = __builtin_amdgcn_mfma_f32_16x16x32_bf16(a1, bj, acc[1][j], 0, 0, 0);
        }
    }

    // fused attention dots: cols of this block are head hd; partial dot per row.
    const int hd = bn >> 8;
    const int cb = (bn & 255) + fm;
    float wsv[8], wdv[8];
    #pragma unroll
    for (int j = 0; j < 8; ++j) {
        wsv[j] = ws_[hd * 256 + cb + j * 16];
        wdv[j] = wd_[hd * 256 + cb + j * 16];
    }
    #pragma unroll
    for (int i = 0; i < 2; ++i) {
        const int rb = bm + wv * 32 + i * 16 + fq * 4;
        #pragma unroll
        for (int r = 0; r < 4; ++r) {
            const int row = rb + r;
            float ps = 0.f, pd = 0.f;
            #pragma unroll
            for (int j = 0; j < 8; ++j) {
                const float av = acc[i][j][r];
                ps += av * wsv[j];
                pd += av * wdv[j];
            }
            #pragma unroll
            for (int o = 8; o > 0; o >>= 1) {
                ps += __shfl_xor(ps, o);
                pd += __shfl_xor(pd, o);
            }
            if (row < M) {
                if (fm == 0) {
                    atomicAdd(&a_s[row * HEADS + hd], ps);
                    atomicAdd(&a_d[row * HEADS + hd], pd);
                }
                #pragma unroll
                for (int j = 0; j < 8; ++j)
                    C[(size_t)row * N + bn + j * 16 + fm] = __float2bfloat16(acc[i][j][r]);
            }
        }
    }
}

// ---------------- layer 1: XCD-sliced gather, 16-lane edge groups, branch-free (r27) -
// Slice mapping (proven r25: FETCH 133MB -> 14MB): slice = blockIdx & 7 -> one XCD,
// per-XCD L2 footprint 2.56MB. Wave = 4 groups x 16 lanes; each group owns one edge,
// each lane covers 8 channels (16B) of the 256B slice row. r26 FAILED (nondeterministic
// absmax): divergent __shfl in the tail guard (ka<cnt varies per group). r27 fix:
// BRANCH-FREE — shfl indices clamped to 0 (lane 0 always owns a valid edge), shuffles
// and loads unconditional, invalid contributions masked by alpha=0.
__global__ __launch_bounds__(256) void gat_gather1(
    const int* __restrict__ offs, const int* __restrict__ nbr,
    const bf16* __restrict__ h1, const float* __restrict__ a_s, const float* __restrict__ a_d,
    const float* __restrict__ bias, bf16* __restrict__ outp)
{
    const int lane = threadIdx.x & 63;
    const int wave = threadIdx.x >> 6;
    const int sl = blockIdx.x & 7;            // slice -> XCD (round-robin heuristic)
    const int n  = (blockIdx.x >> 3) * 4 + wave;
    const int hd = sl >> 1;                   // slice's head
    const int chb = sl * 128;                 // slice channel base
    const int beg = offs[n];
    const int deg = offs[n + 1] - beg;
    const int g  = lane >> 4;                 // edge group 0..3
    const int lg = lane & 15;                 // lane within group

    float acc[8];
    #pragma unroll
    for (int j = 0; j < 8; ++j) acc[j] = 0.f;
    const bf16* hsl = h1 + chb + lg * 8;      // my 8 channels (16B) of the slice

    // branch-free gather: group g handles edges k0+g / k0+4+g; 2x16B in flight/lane.
    auto gshfl = [&](int cnt, int sv, float alv) {
        for (int k0 = 0; k0 < cnt; k0 += 8) {     // wave-uniform loop
            const int ka = k0 + g;
            const int kb = ka + 4;
            const int kac = ka < cnt ? ka : 0;     // clamp: lane 0 always valid
            const int kbc = kb < cnt ? kb : 0;
            const int ska = __shfl(sv, kac);       // uniform exec, all lanes
            const int skb = __shfl(sv, kbc);
            float aa = __shfl(alv, kac);
            float ab = __shfl(alv, kbc);
            aa = ka < cnt ? aa : 0.f;              // mask invalid via alpha
            ab = kb < cnt ? ab : 0.f;
            const uint4 qa = *(const uint4*)(hsl + (size_t)ska * H1DIM);
            const uint4 qb = *(const uint4*)(hsl + (size_t)skb * H1DIM);
            acc[0] += lo2f(qa.x) * aa; acc[1] += hi2f(qa.x) * aa;
            acc[2] += lo2f(qa.y) * aa; acc[3] += hi2f(qa.y) * aa;
            acc[4] += lo2f(qa.z) * aa; acc[5] += hi2f(qa.z) * aa;
            acc[6] += lo2f(qa.w) * aa; acc[7] += hi2f(qa.w) * aa;
            acc[0] += lo2f(qb.x) * ab; acc[1] += hi2f(qb.x) * ab;
            acc[2] += lo2f(qb.y) * ab; acc[3] += hi2f(qb.y) * ab;
            acc[4] += lo2f(qb.z) * ab; acc[5] += hi2f(qb.z) * ab;
            acc[6] += lo2f(qb.w) * ab; acc[7] += hi2f(qb.w) * ab;
        }
    };

    if (deg > 0) {
        const float adn = a_d[n * HEADS + hd];
        if (deg <= 64) {
            // single pass: lane k owns edge k; 1-head softmax via shuffles
            const bool act = lane < deg;
            int s = 0;
            float v = -INFINITY;
            if (act) {
                s = nbr[beg + lane];
                float t = a_s[s * HEADS + hd] + adn;
                v = t > 0.f ? t : NEG_SLOPE * t;
            }
            float m = v;
            #pragma unroll
            for (int o = 32; o > 0; o >>= 1) m = fmaxf(m, __shfl_xor(m, o));
            const float ex = act ? __expf(v - m) : 0.f;
            float sm = ex;
            #pragma unroll
            for (int o = 32; o > 0; o >>= 1) sm += __shfl_xor(sm, o);
            const float al = ex / (sm + 1e-16f);
            gshfl(deg, s, al);
        } else {
            // rare path (deg > 64): in-wave 3-pass streaming softmax, chunked gather
            float m = -INFINITY;
            for (int k = lane; k < deg; k += 64) {
                const int s = nbr[beg + k];
                float t = a_s[s * HEADS + hd] + adn;
                t = t > 0.f ? t : NEG_SLOPE * t;
                m = fmaxf(m, t);
            }
            #pragma unroll
            for (int o = 32; o > 0; o >>= 1) m = fmaxf(m, __shfl_xor(m, o));
            float q = 0.f;
            for (int k = lane; k < deg; k += 64) {
                const int s = nbr[beg + k];
                float t = a_s[s * HEADS + hd] + adn;
                t = t > 0.f ? t : NEG_SLOPE * t;
                q += __expf(t - m);
            }
            #pragma unroll
            for (int o = 32; o > 0; o >>= 1) q += __shfl_xor(q, o);
            const float den = q + 1e-16f;
            for (int bs = 0; bs < deg; bs += 64) {
                const int cnt = min(64, deg - bs);
                int s = 0;
                float al = 0.f;
                if (lane < cnt) {
                    s = nbr[beg + bs + lane];
                    float t = a_s[s * HEADS + hd] + adn;
                    t = t > 0.f ? t : NEG_SLOPE * t;
                    al = __expf(t - m) / den;
                }
                gshfl(cnt, s, al);
            }
        }
    }

    // cross-group reduce: lanes {lg, lg+16, lg+32, lg+48} hold the same 8 channels.
    #pragma unroll
    for (int j = 0; j < 8; ++j) {
        acc[j] += __shfl_xor(acc[j], 16);
        acc[j] += __shfl_xor(acc[j], 32);
    }

    // epilogue (lanes 0..15): bias + ELU + 16B bf16 nt store (256B/node-slice)
    if (lane < 16) {
        const int ch = chb + lane * 8;
        const float4 b0 = *(const float4*)(bias + ch);
        const float4 b1 = *(const float4*)(bias + ch + 4);
        float w[8];
        w[0] = acc[0] + b0.x; w[1] = acc[1] + b0.y;
        w[2] = acc[2] + b0.z; w[3] = acc[3] + b0.w;
        w[4] = acc[4] + b1.x; w[5] = acc[5] + b1.y;
        w[6] = acc[6] + b1.z; w[7] = acc[7] + b1.w;
        #pragma unroll
        for (int j = 0; j < 8; ++j) w[j] = w[j] > 0.f ? w[j] : (__expf(w[j]) - 1.f);
        bf16 ob[8];
        #pragma unroll
        for (int j = 0; j < 8; ++j) ob[j] = __float2bfloat16(w[j]);
        __builtin_nontemporal_store(*(const u32x4*)&ob[0],
                                    (u32x4*)(outp + (size_t)n * H1DIM + ch));
    }
}

// ---------------- layer 2: wave-per-node softmax + gather (r19), fp32 nt out --------
__global__ __launch_bounds__(256) void gat_gather2(
    const int* __restrict__ offs, const int* __restrict__ nbr,
    const bf16* __restrict__ h2, const float* __restrict__ a_s, const float* __restrict__ a_d,
    const float* __restrict__ bias, float* __restrict__ outp)
{
    const int lane = threadIdx.x & 63;
    const int wave = threadIdx.x >> 6;
    const int n = blockIdx.x * 4 + wave;
    const int beg = offs[n];
    const int deg = offs[n + 1] - beg;

    float acc[4] = {0.f, 0.f, 0.f, 0.f};

    // gather cnt edges; 8 edges unrolled => 8 independent 8B loads in flight.
    auto gshfl = [&](int cnt, int sv, float alv) {
        for (int k0 = 0; k0 < cnt; k0 += 8) {
            uint2 q[8];
            float av[8];
            #pragma unroll
            for (int u = 0; u < 8; ++u) {
                const int k = k0 + u;
                if (k < cnt) {                        // wave-uniform branch
                    const int sk = __shfl(sv, k);
                    av[u] = __shfl(alv, k);
                    q[u] = *(const uint2*)(h2 + (size_t)sk * OUT_C + lane * 4);
                } else {
                    q[u] = (uint2){0u, 0u};
                    av[u] = 0.f;
                }
            }
            #pragma unroll
            for (int u = 0; u < 8; ++u) {
                acc[0] += lo2f(q[u].x) * av[u]; acc[1] += hi2f(q[u].x) * av[u];
                acc[2] += lo2f(q[u].y) * av[u]; acc[3] += hi2f(q[u].y) * av[u];
            }
        }
    };

    if (deg > 0) {
        const float adn = a_d[n];
        if (deg <= 64) {
            const bool act = lane < deg;
            int s = 0;
            float v = -INFINITY;
            if (act) {
                s = nbr[beg + lane];
                float t = a_s[s] + adn;
                v = t > 0.f ? t : NEG_SLOPE * t;
            }
            float m = v;
            #pragma unroll
            for (int o = 32; o > 0; o >>= 1) m = fmaxf(m, __shfl_xor(m, o));
            const float ex = act ? __expf(v - m) : 0.f;
            float sm = ex;
            #pragma unroll
            for (int o = 32; o > 0; o >>= 1) sm += __shfl_xor(sm, o);
            const float al = ex / (sm + 1e-16f);
            gshfl(deg, s, al);
        } else {
            float m = -INFINITY;
            for (int k = lane; k < deg; k += 64) {
                const int s = nbr[beg + k];
                float t = a_s[s] + adn;
                t = t > 0.f ? t : NEG_SLOPE * t;
                m = fmaxf(m, t);
            }
            #pragma unroll
            for (int o = 32; o > 0; o >>= 1) m = fmaxf(m, __shfl_xor(m, o));
            float q = 0.f;
            for (int k = lane; k < deg; k += 64) {
                const int s = nbr[beg + k];
                float t = a_s[s] + adn;
                t = t > 0.f ? t : NEG_SLOPE * t;
                q += __expf(t - m);
            }
            #pragma unroll
            for (int o = 32; o > 0; o >>= 1) q += __shfl_xor(q, o);
            const float den = q + 1e-16f;
            for (int bs = 0; bs < deg; bs += 64) {
                const int cnt = min(64, deg - bs);
                int s = 0;
                float al = 0.f;
                if (lane < cnt) {
                    s = nbr[beg + bs + lane];
                    float t = a_s[s] + adn;
                    t = t > 0.f ? t : NEG_SLOPE * t;
                    al = __expf(t - m) / den;
                }
                gshfl(cnt, s, al);
            }
        }
    }

    const int ch = lane * 4;
    const float4 bv = *(const float4*)(bias + ch);
    f32x4 w;
    w[0] = acc[0] + bv.x; w[1] = acc[1] + bv.y;
    w[2] = acc[2] + bv.z; w[3] = acc[3] + bv.w;
    __builtin_nontemporal_store(w, (f32x4*)(outp + (size_t)n * OUT_C + ch));
}

extern "C" void kernel_launch(void* const* d_in, const int* in_sizes, int n_in,
                              void* d_out, int out_size, void* d_ws, size_t ws_size,
                              hipStream_t stream) {
    (void)in_sizes; (void)n_in; (void)out_size; (void)ws_size;
    const float* x        = (const float*)d_in[0];
    const int*   ei       = (const int*)d_in[1];   // int32 [2,E] (verified round 4)
    const float* W1       = (const float*)d_in[2];
    const float* att_src1 = (const float*)d_in[3];
    const float* att_dst1 = (const float*)d_in[4];
    const float* b1       = (const float*)d_in[5];
    const float* W2       = (const float*)d_in[6];
    const float* att_src2 = (const float*)d_in[7];
    const float* att_dst2 = (const float*)d_in[8];
    const float* b2       = (const float*)d_in[9];
    float* out = (float*)d_out;

    // ---- workspace carve (all 256B-aligned) ----
    char* base = (char*)d_ws;
    size_t woff = 0;
    auto carve = [&](size_t bytes) -> char* {
        char* p = base + woff;
        woff += (bytes + 255) & ~(size_t)255;
        return p;
    };
    bf16* h1   = (bf16*)carve((size_t)N_NODES * H1DIM * 2);   // 20.48 MB
    bf16* a2   = (bf16*)carve((size_t)N_NODES * H1DIM * 2);   // 20.48 MB
    bf16* h2   = (bf16*)carve((size_t)N_NODES * OUT_C * 2);   //  5.12 MB
    bf16* xb   = (bf16*)carve((size_t)N_NODES * IN_C * 2);    // 15.36 MB
    bf16* W1t  = (bf16*)carve((size_t)H1DIM * IN_C * 2);
    bf16* W2t  = (bf16*)carve((size_t)OUT_C * H1DIM * 2);
    // NOTE: as1..degs must stay CONTIGUOUS — prep_kernel zeroes the whole span.
    // Zeroing is REQUIRED for the fused-atomic att dots (as1/ad1/as2/ad2 accumulate).
    float* as1 = (float*)carve((size_t)N_NODES * HEADS * 4);  // 160000 B
    float* ad1 = (float*)carve((size_t)N_NODES * HEADS * 4);  // 160000 B
    float* as2 = (float*)carve((size_t)N_NODES * 4);          // 40000 -> 40192 B
    float* ad2 = (float*)carve((size_t)N_NODES * 4);          // 40000 -> 40192 B
    int* degs  = (int*)carve((size_t)4 * N_NODES * 4);        // 160000 B
    int* deg_d = degs;
    int* deg_s = degs + N_NODES;
    int* cur_d = degs + 2 * N_NODES;
    int* cur_s = degs + 3 * N_NODES;
    int* offs_d = (int*)carve((size_t)(N_NODES + 1) * 4);
    int* offs_s = (int*)carve((size_t)(N_NODES + 1) * 4);
    int* nbr_d  = (int*)carve((size_t)N_EDGES * 4);
    int* nbr_s  = (int*)carve((size_t)N_EDGES * 4);

    // ---- fused prep: cvt + transposes + zero(as1..degs) ----
    prep_kernel<<<CVT_BLOCKS + T1_BLOCKS + T2_BLOCKS + Z_BLOCKS, 256, 0, stream>>>(
        x, xb, W1, W1t, W2, W2t, (int*)as1);

    // ---- CSR build ----
    count_deg<<<(N_EDGES + 255) / 256, 256, 0, stream>>>(ei, deg_d, deg_s);
    scan_fast2<<<2, 1024, 0, stream>>>(deg_d, offs_d, deg_s, offs_s, N_NODES);
    fill_csr<<<(N_EDGES + 255) / 256, 256, 0, stream>>>(ei, offs_d, offs_s, cur_d, cur_s, nbr_d, nbr_s);

    // ---- layer 1: GEMM with fused att dots, then XCD-sliced gather ----
    gemm_mfma128<<<dim3(H1DIM / 128, (N_NODES + 127) / 128), 256, 0, stream>>>(
        xb, W1t, h1, att_src1, att_dst1, as1, ad1, N_NODES, H1DIM, IN_C);
    gat_gather1<<<(N_NODES / 4) * 8, 256, 0, stream>>>(offs_d, nbr_d, h1, as1, ad1, b1, a2);

    // ---- layer 2: GEMM with fused att dots, then gather ----
    gemm_mfma64<<<dim3(OUT_C / 64, (N_NODES + 127) / 128), 256, 0, stream>>>(
        a2, W2t, h2, att_src2, att_dst2, as2, ad2, N_NODES, OUT_C, H1DIM);
    gat_gather2<<<N_NODES / 4, 256, 0, stream>>>(offs_s, nbr_s, h2, as2, ad2, b2, out);
}